// Round 1
// baseline (271.434 us; speedup 1.0000x reference)
//
#include <hip/hip_runtime.h>
#include <hip/hip_bf16.h>

#define TPB 256
#define PREP_BLOCKS 64

typedef __attribute__((ext_vector_type(8))) short short8;
typedef __attribute__((ext_vector_type(4))) float f32x4;

// ---- weight image byte offsets in d_ws (read directly from global/L2) ----
#define G_W2F   0        // [t=3][s=4][lane=64][j=8] bf16  12288
#define G_MVF   12288    // [s=4][64][8] bf16               4096
#define G_D1F   16384    // [t=2][64][8] bf16               2048
#define G_D2F   18432    // [64][8] bf16                    1024
#define G_CEAB  19456    // [e=4][n=128][4] bf16 {a0,a1,a2,ce} 4096
#define G_B2P   23552    // [48] f32 (pad 0)
#define G_B3    23744    // [128] f32
#define G_BMV   24256    // [16] f32 (bm|bv)
#define G_D1C   24320    // [32] f32 (Wd1 col0 + bd1)
#define G_BD2   24448    // [16] f32 (pad 0)
#define G_W3F   24512    // [nt=8][s=2][64][8] bf16        16384
#define G_END   40896

// ---- per-wave LDS region (strides padded for bank spread, 16B-aligned rows) ----
#define PW_SWC  0        // [16][12] f32 (768)
#define PW_SIC  768      // [16][40] bf16 (1280) decoder input, k-major per row
#define PW_ST   2048     // [16][72] bf16 (2304) s-tile (cols 0..63 used)
#define PW_BUF  4352     // [16][136] bf16 (4352) x1-tile per edge / x3-tile
#define PW_MH   8704     // union: [16][18] f32 mlv (1152) | [16][40] bf16 ht (1280)
#define PW_SZ   9984
#define LDS_TOT (4 * PW_SZ)   // 39936 B -> 4 blocks/CU (was 64448 -> 2 blocks/CU)

__device__ __forceinline__ unsigned short f2bf(float f) {
    unsigned int u = __float_as_uint(f);
    unsigned int r = u + 0x7fffu + ((u >> 16) & 1u);   // RNE
    return (unsigned short)(r >> 16);
}
__device__ __forceinline__ unsigned int pk(float a, float b) {
    __hip_bfloat162 h = __float22bfloat162_rn(make_float2(a, b));
    unsigned int u; __builtin_memcpy(&u, &h, 4); return u;
}
__device__ __forceinline__ unsigned short bfbits(float v) {
    return (unsigned short)(pk(v, v) & 0xffffu);
}

__global__ void prep_kernel(
    const float* __restrict__ W1, const float* __restrict__ b1,
    const float* __restrict__ W2, const float* __restrict__ b2,
    const float* __restrict__ W3, const float* __restrict__ b3,
    const float* __restrict__ Wm, const float* __restrict__ bm,
    const float* __restrict__ Wv, const float* __restrict__ bv,
    const float* __restrict__ Wd1, const float* __restrict__ bd1,
    const float* __restrict__ Wd2, const float* __restrict__ bd2,
    unsigned char* __restrict__ ws)
{
    const int g0 = blockIdx.x * TPB + threadIdx.x;
    const int gs = gridDim.x * TPB;
    unsigned short* w2f = (unsigned short*)(ws + G_W2F);
    for (int i = g0; i < 6144; i += gs) {           // B[k][n] = W2[n][k]
        int j = i & 7, lane = (i >> 3) & 63, ts = i >> 9;
        int tt = ts >> 2, s = ts & 3;
        int n = 16 * tt + (lane & 15), k = 32 * s + 8 * (lane >> 4) + j;
        w2f[i] = (n < 39) ? f2bf(W2[n * 128 + k]) : 0;
    }
    unsigned short* w3f = (unsigned short*)(ws + G_W3F);
    for (int i = g0; i < 8192; i += gs) {           // B[k][n] = W3[n][k]
        int j = i & 7, lane = (i >> 3) & 63, ns = i >> 9;
        int nt = ns >> 1, s = ns & 1;
        int n = 16 * nt + (lane & 15), k = 32 * s + 8 * (lane >> 4) + j;
        w3f[i] = (k < 39) ? f2bf(W3[n * 39 + k]) : 0;
    }
    unsigned short* mvf = (unsigned short*)(ws + G_MVF);
    for (int i = g0; i < 2048; i += gs) {           // n<8: Wm, n>=8: Wv
        int j = i & 7, lane = (i >> 3) & 63, s = i >> 9;
        int n = lane & 15, k = 32 * s + 8 * (lane >> 4) + j;
        mvf[i] = f2bf(n < 8 ? Wm[n * 128 + k] : Wv[(n - 8) * 128 + k]);
    }
    unsigned short* d1f = (unsigned short*)(ws + G_D1F);
    for (int i = g0; i < 1024; i += gs) {           // k<20 -> Wd1[n][5+k]
        int j = i & 7, lane = (i >> 3) & 63, tt = i >> 9;
        int n = 16 * tt + (lane & 15), k = 8 * (lane >> 4) + j;
        d1f[i] = (k < 20) ? f2bf(Wd1[n * 25 + 5 + k]) : 0;
    }
    unsigned short* d2f = (unsigned short*)(ws + G_D2F);
    for (int i = g0; i < 512; i += gs) {
        int j = i & 7, lane = i >> 3;
        int n = lane & 15, k = 8 * (lane >> 4) + j;
        d2f[i] = (n < 12) ? f2bf(Wd2[n * 32 + k]) : 0;
    }
    unsigned short* ceab = (unsigned short*)(ws + G_CEAB);
    for (int i = g0; i < 2048; i += gs) {           // [e][n][4] {a0,a1,a2,ce}
        int c = i & 3, n = (i >> 2) & 127, e = i >> 9;
        float v = (c < 3) ? W1[n * 13 + 10 + c]
                          : (W1[n * 13 + 0] + W1[n * 13 + 6 + e] + b1[n]);
        ceab[i] = f2bf(v);
    }
    float* fb = (float*)(ws + G_B2P);
    for (int i = g0; i < 48; i += gs) fb[i] = (i < 39) ? b2[i] : 0.f;
    fb = (float*)(ws + G_B3);
    for (int i = g0; i < 128; i += gs) fb[i] = b3[i];
    fb = (float*)(ws + G_BMV);
    for (int i = g0; i < 16; i += gs) fb[i] = (i < 8) ? bm[i] : bv[i - 8];
    fb = (float*)(ws + G_D1C);
    for (int i = g0; i < 32; i += gs) fb[i] = Wd1[i * 25 + 0] + bd1[i];
    fb = (float*)(ws + G_BD2);
    for (int i = g0; i < 16; i += gs) fb[i] = (i < 12) ? bd2[i] : 0.f;
}

union S8 { short8 v; uint4 u; };

__global__ __launch_bounds__(TPB, 4) void vae_mfma(
    const float* __restrict__ ic, const float* __restrict__ cc,
    const float* __restrict__ eps,
    const unsigned char* __restrict__ ws,
    float* __restrict__ out, int B)
{
    // Per-wave scratch only. Weight image stays in global (L2-hot, ~40KB,
    // read once per lane into registers) — dropping its LDS copy cuts LDS
    // 64448 -> 39936 B: 2 -> 4 blocks/CU, 2 -> 4 waves/SIMD.
    __shared__ __attribute__((aligned(16))) unsigned char lds[LDS_TOT];
    const int tid = threadIdx.x;

    const int lane = tid & 63, w = tid >> 6;
    const int quad = lane >> 4, n16 = lane & 15;
    const bool q0 = (quad == 0);
    const long rb = ((long)blockIdx.x * 4 + w) * 16;
    unsigned char* pw = lds + w * PW_SZ;

    // ---- stage cc (fp32 p's) and ic (bf16 decoder k=0..11); zero pads ----
    {
        int r = lane >> 2, g = lane & 3;
        long R = rb + r;
        const int cbase[4] = {0, 2, 10, 12};
        const int csing[4] = {14, 18, 22, 26};
        const float* crow = cc + R * 30;
        const float* irow = ic + R * 30;
        float2 cp = *(const float2*)(crow + cbase[g]);
        float  cs = crow[csing[g]];
        float2 ip = *(const float2*)(irow + cbase[g]);
        float  is = irow[csing[g]];
        float* swc = (float*)(pw + PW_SWC);
        *(float2*)(swc + r * 12 + 2 * g) = cp;
        swc[r * 12 + 8 + g] = cs;
        unsigned short* sic = (unsigned short*)(pw + PW_SIC);
        *(unsigned int*)(sic + r * 40 + 2 * g) = pk(ip.x, ip.y);
        sic[r * 40 + 8 + g] = bfbits(is);
        if (g < 3) *(unsigned long long*)(sic + r * 40 + 20 + 4 * g) = 0ull; // k=20..31
        unsigned short* st = (unsigned short*)(pw + PW_ST);
        *(unsigned long long*)(st + r * 72 + 48 + 4 * g) = 0ull;             // cols 48..63
    }

    // ---- W2 B-fragments + biases (direct from L2-hot global) ----
    short8 B2[12];
    #pragma unroll
    for (int ts = 0; ts < 12; ts++) {
        S8 x; x.u = *(const uint4*)(ws + G_W2F + (ts * 64 + lane) * 16);
        B2[ts] = x.v;
    }
    const float b2v0 = *(const float*)(ws + G_B2P + n16 * 4);
    const float b2v1 = *(const float*)(ws + G_B2P + (16 + n16) * 4);
    const float b2v2 = *(const float*)(ws + G_B2P + (32 + n16) * 4);

    // p-values for this lane's row (n16)
    float pa[4], pb[4], pc[4];
    {
        const float* swcr = (const float*)(pw + PW_SWC) + n16 * 12;
        float4 t0 = *(const float4*)(swcr);
        float4 t1 = *(const float4*)(swcr + 4);
        float4 t2 = *(const float4*)(swcr + 8);
        pa[0] = t0.x; pa[1] = t0.y; pa[2] = t0.z; pa[3] = t0.w;
        pb[0] = t1.x; pb[1] = t1.y; pb[2] = t1.z; pb[3] = t1.w;
        pc[0] = t2.x; pc[1] = t2.y; pc[2] = t2.z; pc[3] = t2.w;
    }

    f32x4 ss0 = {0,0,0,0}, ss1 = {0,0,0,0}, ss2 = {0,0,0,0};
    unsigned short* x1t = (unsigned short*)(pw + PW_BUF);

    // ---- message MLP: L1 via MFMA (bias in k=3), relayout, L2 via MFMA ----
    #pragma unroll
    for (int e = 0; e < 4; e++) {
        S8 a1;
        a1.u.x = q0 ? pk(pa[e], pb[e]) : 0u;
        a1.u.y = q0 ? pk(pc[e], 1.0f) : 0u;
        a1.u.z = 0u; a1.u.w = 0u;
        const unsigned long long* cb =
            (const unsigned long long*)(ws + G_CEAB + e * 1024);
        f32x4 cr[8];
        #pragma unroll
        for (int nt = 0; nt < 8; nt++) {
            unsigned long long bw = cb[nt * 16 + n16];
            S8 bf;
            bf.u.x = q0 ? (unsigned int)bw : 0u;
            bf.u.y = q0 ? (unsigned int)(bw >> 32) : 0u;
            bf.u.z = 0u; bf.u.w = 0u;
            f32x4 z = {0, 0, 0, 0};
            cr[nt] = __builtin_amdgcn_mfma_f32_16x16x32_bf16(a1.v, bf.v, z, 0, 0, 0);
        }
        #pragma unroll
        for (int nt = 0; nt < 8; nt++) {
            #pragma unroll
            for (int r = 0; r < 4; r++)
                x1t[(quad * 4 + r) * 136 + nt * 16 + n16] = bfbits(fmaxf(cr[nt][r], 0.f));
        }
        f32x4 c0 = {b2v0, b2v0, b2v0, b2v0};
        f32x4 c1 = {b2v1, b2v1, b2v1, b2v1};
        f32x4 c2 = {b2v2, b2v2, b2v2, b2v2};
        #pragma unroll
        for (int s = 0; s < 4; s++) {
            S8 a2; a2.u = *(const uint4*)(x1t + n16 * 136 + s * 32 + quad * 8);
            c0 = __builtin_amdgcn_mfma_f32_16x16x32_bf16(a2.v, B2[s],     c0, 0, 0, 0);
            c1 = __builtin_amdgcn_mfma_f32_16x16x32_bf16(a2.v, B2[4 + s], c1, 0, 0, 0);
            c2 = __builtin_amdgcn_mfma_f32_16x16x32_bf16(a2.v, B2[8 + s], c2, 0, 0, 0);
        }
        #pragma unroll
        for (int r = 0; r < 4; r++) {
            ss0[r] += fmaxf(c0[r], 0.f);
            ss1[r] += fmaxf(c1[r], 0.f);
            ss2[r] += fmaxf(c2[r], 0.f);
        }
    }

    // ---- relayout s: C-layout -> [row][k] bf16 (stride 72) ----
    unsigned short* st = (unsigned short*)(pw + PW_ST);
    #pragma unroll
    for (int r = 0; r < 4; r++) {
        int row = quad * 4 + r;
        st[row * 72 + n16]      = bfbits(ss0[r]);
        st[row * 72 + 16 + n16] = bfbits(ss1[r]);
        st[row * 72 + 32 + n16] = bfbits(ss2[r]);   // cols 39..47 exact zeros
    }

    // ---- L3: A from st, B streamed from global (L2-resident) ----
    S8 A30, A31;
    A30.u = *(const uint4*)(st + n16 * 72 + quad * 8);
    A31.u = *(const uint4*)(st + n16 * 72 + 32 + quad * 8);
    const uint4* w3g = (const uint4*)(ws + G_W3F);
    unsigned short* x3t = (unsigned short*)(pw + PW_BUF);   // reuse BUF
    const float* b3p = (const float*)(ws + G_B3);
    #pragma unroll
    for (int nt = 0; nt < 8; nt++) {
        float bb = b3p[nt * 16 + n16];
        f32x4 c = {bb, bb, bb, bb};
        S8 bf0, bf1;
        bf0.u = w3g[(nt * 2 + 0) * 64 + lane];
        bf1.u = w3g[(nt * 2 + 1) * 64 + lane];
        c = __builtin_amdgcn_mfma_f32_16x16x32_bf16(A30.v, bf0.v, c, 0, 0, 0);
        c = __builtin_amdgcn_mfma_f32_16x16x32_bf16(A31.v, bf1.v, c, 0, 0, 0);
        #pragma unroll
        for (int r = 0; r < 4; r++)
            x3t[(quad * 4 + r) * 136 + nt * 16 + n16] = bfbits(fmaxf(c[r], 0.f));
    }

    // ---- heads: means|logvar (N=16) ----
    S8 Ah0, Ah1, Ah2, Ah3;
    Ah0.u = *(const uint4*)(x3t + n16 * 136 + 0  + quad * 8);
    Ah1.u = *(const uint4*)(x3t + n16 * 136 + 32 + quad * 8);
    Ah2.u = *(const uint4*)(x3t + n16 * 136 + 64 + quad * 8);
    Ah3.u = *(const uint4*)(x3t + n16 * 136 + 96 + quad * 8);
    float bmvv = *(const float*)(ws + G_BMV + n16 * 4);
    f32x4 cm = {bmvv, bmvv, bmvv, bmvv};
    {
        S8 bm0; bm0.u = *(const uint4*)(ws + G_MVF + (0 * 64 + lane) * 16);
        cm = __builtin_amdgcn_mfma_f32_16x16x32_bf16(Ah0.v, bm0.v, cm, 0, 0, 0);
        S8 bm1; bm1.u = *(const uint4*)(ws + G_MVF + (1 * 64 + lane) * 16);
        cm = __builtin_amdgcn_mfma_f32_16x16x32_bf16(Ah1.v, bm1.v, cm, 0, 0, 0);
        S8 bm2; bm2.u = *(const uint4*)(ws + G_MVF + (2 * 64 + lane) * 16);
        cm = __builtin_amdgcn_mfma_f32_16x16x32_bf16(Ah2.v, bm2.v, cm, 0, 0, 0);
        S8 bm3; bm3.u = *(const uint4*)(ws + G_MVF + (3 * 64 + lane) * 16);
        cm = __builtin_amdgcn_mfma_f32_16x16x32_bf16(Ah3.v, bm3.v, cm, 0, 0, 0);
    }
    float* mlv = (float*)(pw + PW_MH);
    #pragma unroll
    for (int r = 0; r < 4; r++) mlv[(quad * 4 + r) * 18 + n16] = cm[r];

    // ---- reparameterization + means/logvar/z outputs ----
    {
        int r = lane >> 2, g = lane & 3;
        long R = rb + r;
        const float* mrow = mlv + r * 18;
        float2 mn = *(const float2*)(mrow + 2 * g);
        float2 lv = *(const float2*)(mrow + 8 + 2 * g);
        float2 ev = *(const float2*)(eps + R * 8 + 2 * g);
        float z0 = fmaf(ev.x, __expf(0.5f * lv.x), mn.x);
        float z1 = fmaf(ev.y, __expf(0.5f * lv.y), mn.y);
        *(float2*)(out + (long)B * 12 + R * 8 + 2 * g) = mn;
        *(float2*)(out + (long)B * 20 + R * 8 + 2 * g) = lv;
        *(float2*)(out + (long)B * 28 + R * 8 + 2 * g) = make_float2(z0, z1);
        unsigned short* sic = (unsigned short*)(pw + PW_SIC);
        *(unsigned int*)(sic + r * 40 + 12 + 2 * g) = pk(z0, z1);  // k=12..19
    }

    // ---- decoder layer 1 (N=32, K=32) ----
    S8 Ad;
    Ad.u = *(const uint4*)((const unsigned short*)(pw + PW_SIC) + n16 * 40 + quad * 8);
    unsigned short* ht = (unsigned short*)(pw + PW_MH);   // reuse MH (mlv consumed)
    #pragma unroll
    for (int t = 0; t < 2; t++) {
        float dc = *(const float*)(ws + G_D1C + (t * 16 + n16) * 4);
        f32x4 c = {dc, dc, dc, dc};
        S8 bd; bd.u = *(const uint4*)(ws + G_D1F + (t * 64 + lane) * 16);
        c = __builtin_amdgcn_mfma_f32_16x16x32_bf16(Ad.v, bd.v, c, 0, 0, 0);
        #pragma unroll
        for (int r = 0; r < 4; r++)
            ht[(quad * 4 + r) * 40 + t * 16 + n16] = bfbits(fmaxf(c[r], 0.f));
    }

    // ---- decoder layer 2 (N=16, K=32) + sigmoid + recon store ----
    S8 Ah2d; Ah2d.u = *(const uint4*)(ht + n16 * 40 + quad * 8);
    float bd2v = *(const float*)(ws + G_BD2 + n16 * 4);
    f32x4 cr2 = {bd2v, bd2v, bd2v, bd2v};
    S8 b2d; b2d.u = *(const uint4*)(ws + G_D2F + lane * 16);
    cr2 = __builtin_amdgcn_mfma_f32_16x16x32_bf16(Ah2d.v, b2d.v, cr2, 0, 0, 0);
    if (n16 < 12) {
        #pragma unroll
        for (int r = 0; r < 4; r++)
            out[(rb + quad * 4 + r) * 12 + n16] = 1.f / (1.f + __expf(-cr2[r]));
    }
}

extern "C" void kernel_launch(void* const* d_in, const int* in_sizes, int n_in,
                              void* d_out, int out_size, void* d_ws, size_t ws_size,
                              hipStream_t stream) {
    const float* ic  = (const float*)d_in[0];   // initial_c [B,30]
    const float* cc  = (const float*)d_in[2];   // current_c [B,30]
    const float* eps = (const float*)d_in[3];   // eps [B,8]

    const int B = in_sizes[3] / 8;              // 262144
    const int nblocks = B / 64;                 // 4096

    prep_kernel<<<PREP_BLOCKS, TPB, 0, stream>>>(
        (const float*)d_in[4],  (const float*)d_in[5],
        (const float*)d_in[6],  (const float*)d_in[7],
        (const float*)d_in[8],  (const float*)d_in[9],
        (const float*)d_in[10], (const float*)d_in[11],
        (const float*)d_in[12], (const float*)d_in[13],
        (const float*)d_in[14], (const float*)d_in[15],
        (const float*)d_in[16], (const float*)d_in[17],
        (unsigned char*)d_ws);
    vae_mfma<<<nblocks, TPB, 0, stream>>>(
        ic, cc, eps, (const unsigned char*)d_ws, (float*)d_out, B);
}

// Round 2
// 191.756 us; speedup vs baseline: 1.4155x; 1.4155x over previous
//
#include <hip/hip_runtime.h>
#include <hip/hip_bf16.h>

#define TPB 256
#define PREP_BLOCKS 64

typedef __attribute__((ext_vector_type(8))) short short8;
typedef __attribute__((ext_vector_type(4))) float f32x4;

// ---- weight image byte offsets in d_ws (read directly from global/L2) ----
#define G_W2F   0        // [t=3][s=4][lane=64][j=8] bf16  12288
#define G_MVF   12288    // [s=4][64][8] bf16               4096
#define G_D1F   16384    // [t=2][64][8] bf16               2048
#define G_D2F   18432    // [64][8] bf16                    1024
#define G_CEAB  19456    // [e=4][n=128][4] bf16 {a0,a1,a2,ce} 4096
#define G_B2P   23552    // [48] f32 (pad 0)
#define G_B3    23744    // [128] f32
#define G_BMV   24256    // [16] f32 (bm|bv)
#define G_D1C   24320    // [32] f32 (Wd1 col0 + bd1)
#define G_BD2   24448    // [16] f32 (pad 0)
#define G_W3F   24512    // [nt=8][s=2][64][8] bf16        16384
#define G_END   40896

// ---- per-wave LDS region (strides padded for bank spread, 16B-aligned rows) ----
#define PW_SWC  0        // [16][12] f32 (768)
#define PW_SIC  768      // [16][40] bf16 (1280) decoder input, k-major per row
#define PW_ST   2048     // [16][72] bf16 (2304) s-tile (cols 0..63 used)
#define PW_BUF  4352     // [16][136] bf16 (4352) x1-tile per edge / x3-tile
#define PW_MH   8704     // union: [16][18] f32 mlv (1152) | [16][40] bf16 ht (1280)
#define PW_SZ   9984
#define LDS_TOT (4 * PW_SZ)   // 39936 B -> 4 blocks/CU

__device__ __forceinline__ unsigned short f2bf(float f) {
    unsigned int u = __float_as_uint(f);
    unsigned int r = u + 0x7fffu + ((u >> 16) & 1u);   // RNE
    return (unsigned short)(r >> 16);
}
__device__ __forceinline__ unsigned int pk(float a, float b) {
    __hip_bfloat162 h = __float22bfloat162_rn(make_float2(a, b));
    unsigned int u; __builtin_memcpy(&u, &h, 4); return u;
}
__device__ __forceinline__ unsigned short bfbits(float v) {
    return (unsigned short)(pk(v, v) & 0xffffu);
}

__global__ void prep_kernel(
    const float* __restrict__ W1, const float* __restrict__ b1,
    const float* __restrict__ W2, const float* __restrict__ b2,
    const float* __restrict__ W3, const float* __restrict__ b3,
    const float* __restrict__ Wm, const float* __restrict__ bm,
    const float* __restrict__ Wv, const float* __restrict__ bv,
    const float* __restrict__ Wd1, const float* __restrict__ bd1,
    const float* __restrict__ Wd2, const float* __restrict__ bd2,
    unsigned char* __restrict__ ws)
{
    const int g0 = blockIdx.x * TPB + threadIdx.x;
    const int gs = gridDim.x * TPB;
    unsigned short* w2f = (unsigned short*)(ws + G_W2F);
    for (int i = g0; i < 6144; i += gs) {           // B[k][n] = W2[n][k]
        int j = i & 7, lane = (i >> 3) & 63, ts = i >> 9;
        int tt = ts >> 2, s = ts & 3;
        int n = 16 * tt + (lane & 15), k = 32 * s + 8 * (lane >> 4) + j;
        w2f[i] = (n < 39) ? f2bf(W2[n * 128 + k]) : 0;
    }
    unsigned short* w3f = (unsigned short*)(ws + G_W3F);
    for (int i = g0; i < 8192; i += gs) {           // B[k][n] = W3[n][k]
        int j = i & 7, lane = (i >> 3) & 63, ns = i >> 9;
        int nt = ns >> 1, s = ns & 1;
        int n = 16 * nt + (lane & 15), k = 32 * s + 8 * (lane >> 4) + j;
        w3f[i] = (k < 39) ? f2bf(W3[n * 39 + k]) : 0;
    }
    unsigned short* mvf = (unsigned short*)(ws + G_MVF);
    for (int i = g0; i < 2048; i += gs) {           // n<8: Wm, n>=8: Wv
        int j = i & 7, lane = (i >> 3) & 63, s = i >> 9;
        int n = lane & 15, k = 32 * s + 8 * (lane >> 4) + j;
        mvf[i] = f2bf(n < 8 ? Wm[n * 128 + k] : Wv[(n - 8) * 128 + k]);
    }
    unsigned short* d1f = (unsigned short*)(ws + G_D1F);
    for (int i = g0; i < 1024; i += gs) {           // k<20 -> Wd1[n][5+k]
        int j = i & 7, lane = (i >> 3) & 63, tt = i >> 9;
        int n = 16 * tt + (lane & 15), k = 8 * (lane >> 4) + j;
        d1f[i] = (k < 20) ? f2bf(Wd1[n * 25 + 5 + k]) : 0;
    }
    unsigned short* d2f = (unsigned short*)(ws + G_D2F);
    for (int i = g0; i < 512; i += gs) {
        int j = i & 7, lane = i >> 3;
        int n = lane & 15, k = 8 * (lane >> 4) + j;
        d2f[i] = (n < 12) ? f2bf(Wd2[n * 32 + k]) : 0;
    }
    unsigned short* ceab = (unsigned short*)(ws + G_CEAB);
    for (int i = g0; i < 2048; i += gs) {           // [e][n][4] {a0,a1,a2,ce}
        int c = i & 3, n = (i >> 2) & 127, e = i >> 9;
        float v = (c < 3) ? W1[n * 13 + 10 + c]
                          : (W1[n * 13 + 0] + W1[n * 13 + 6 + e] + b1[n]);
        ceab[i] = f2bf(v);
    }
    float* fb = (float*)(ws + G_B2P);
    for (int i = g0; i < 48; i += gs) fb[i] = (i < 39) ? b2[i] : 0.f;
    fb = (float*)(ws + G_B3);
    for (int i = g0; i < 128; i += gs) fb[i] = b3[i];
    fb = (float*)(ws + G_BMV);
    for (int i = g0; i < 16; i += gs) fb[i] = (i < 8) ? bm[i] : bv[i - 8];
    fb = (float*)(ws + G_D1C);
    for (int i = g0; i < 32; i += gs) fb[i] = Wd1[i * 25 + 0] + bd1[i];
    fb = (float*)(ws + G_BD2);
    for (int i = g0; i < 16; i += gs) fb[i] = (i < 12) ? bd2[i] : 0.f;
}

union S8 { short8 v; uint4 u; };

// __launch_bounds__(TPB, 2): 2 here is the VGPR-cap hint only (cap 128, kernel
// uses ~88, zero spill). Real occupancy is LDS-limited: 39936 B -> 4 blocks/CU
// = 4 waves/SIMD. (TPB,4) capped VGPRs at 64 -> massive scratch spill, 2x slower.
__global__ __launch_bounds__(TPB, 2) void vae_mfma(
    const float* __restrict__ ic, const float* __restrict__ cc,
    const float* __restrict__ eps,
    const unsigned char* __restrict__ ws,
    float* __restrict__ out, int B)
{
    __shared__ __attribute__((aligned(16))) unsigned char lds[LDS_TOT];
    const int tid = threadIdx.x;

    const int lane = tid & 63, w = tid >> 6;
    const int quad = lane >> 4, n16 = lane & 15;
    const bool q0 = (quad == 0);
    const long rb = ((long)blockIdx.x * 4 + w) * 16;
    unsigned char* pw = lds + w * PW_SZ;

    // ---- stage cc (fp32 p's) and ic (bf16 decoder k=0..11); zero pads ----
    {
        int r = lane >> 2, g = lane & 3;
        long R = rb + r;
        const int cbase[4] = {0, 2, 10, 12};
        const int csing[4] = {14, 18, 22, 26};
        const float* crow = cc + R * 30;
        const float* irow = ic + R * 30;
        float2 cp = *(const float2*)(crow + cbase[g]);
        float  cs = crow[csing[g]];
        float2 ip = *(const float2*)(irow + cbase[g]);
        float  is = irow[csing[g]];
        float* swc = (float*)(pw + PW_SWC);
        *(float2*)(swc + r * 12 + 2 * g) = cp;
        swc[r * 12 + 8 + g] = cs;
        unsigned short* sic = (unsigned short*)(pw + PW_SIC);
        *(unsigned int*)(sic + r * 40 + 2 * g) = pk(ip.x, ip.y);
        sic[r * 40 + 8 + g] = bfbits(is);
        if (g < 3) *(unsigned long long*)(sic + r * 40 + 20 + 4 * g) = 0ull; // k=20..31
        unsigned short* st = (unsigned short*)(pw + PW_ST);
        *(unsigned long long*)(st + r * 72 + 48 + 4 * g) = 0ull;             // cols 48..63
    }

    // ---- W2 B-fragments + biases (direct from L2-hot global) ----
    short8 B2[12];
    #pragma unroll
    for (int ts = 0; ts < 12; ts++) {
        S8 x; x.u = *(const uint4*)(ws + G_W2F + (ts * 64 + lane) * 16);
        B2[ts] = x.v;
    }
    const float b2v0 = *(const float*)(ws + G_B2P + n16 * 4);
    const float b2v1 = *(const float*)(ws + G_B2P + (16 + n16) * 4);
    const float b2v2 = *(const float*)(ws + G_B2P + (32 + n16) * 4);

    // p-values for this lane's row (n16)
    float pa[4], pb[4], pc[4];
    {
        const float* swcr = (const float*)(pw + PW_SWC) + n16 * 12;
        float4 t0 = *(const float4*)(swcr);
        float4 t1 = *(const float4*)(swcr + 4);
        float4 t2 = *(const float4*)(swcr + 8);
        pa[0] = t0.x; pa[1] = t0.y; pa[2] = t0.z; pa[3] = t0.w;
        pb[0] = t1.x; pb[1] = t1.y; pb[2] = t1.z; pb[3] = t1.w;
        pc[0] = t2.x; pc[1] = t2.y; pc[2] = t2.z; pc[3] = t2.w;
    }

    f32x4 ss0 = {0,0,0,0}, ss1 = {0,0,0,0}, ss2 = {0,0,0,0};
    unsigned short* x1t = (unsigned short*)(pw + PW_BUF);

    // ---- message MLP: L1 via MFMA (bias in k=3), relayout, L2 via MFMA ----
    #pragma unroll
    for (int e = 0; e < 4; e++) {
        S8 a1;
        a1.u.x = q0 ? pk(pa[e], pb[e]) : 0u;
        a1.u.y = q0 ? pk(pc[e], 1.0f) : 0u;
        a1.u.z = 0u; a1.u.w = 0u;
        const unsigned long long* cb =
            (const unsigned long long*)(ws + G_CEAB + e * 1024);
        f32x4 cr[8];
        #pragma unroll
        for (int nt = 0; nt < 8; nt++) {
            unsigned long long bw = cb[nt * 16 + n16];
            S8 bf;
            bf.u.x = q0 ? (unsigned int)bw : 0u;
            bf.u.y = q0 ? (unsigned int)(bw >> 32) : 0u;
            bf.u.z = 0u; bf.u.w = 0u;
            f32x4 z = {0, 0, 0, 0};
            cr[nt] = __builtin_amdgcn_mfma_f32_16x16x32_bf16(a1.v, bf.v, z, 0, 0, 0);
        }
        #pragma unroll
        for (int nt = 0; nt < 8; nt++) {
            #pragma unroll
            for (int r = 0; r < 4; r++)
                x1t[(quad * 4 + r) * 136 + nt * 16 + n16] = bfbits(fmaxf(cr[nt][r], 0.f));
        }
        f32x4 c0 = {b2v0, b2v0, b2v0, b2v0};
        f32x4 c1 = {b2v1, b2v1, b2v1, b2v1};
        f32x4 c2 = {b2v2, b2v2, b2v2, b2v2};
        #pragma unroll
        for (int s = 0; s < 4; s++) {
            S8 a2; a2.u = *(const uint4*)(x1t + n16 * 136 + s * 32 + quad * 8);
            c0 = __builtin_amdgcn_mfma_f32_16x16x32_bf16(a2.v, B2[s],     c0, 0, 0, 0);
            c1 = __builtin_amdgcn_mfma_f32_16x16x32_bf16(a2.v, B2[4 + s], c1, 0, 0, 0);
            c2 = __builtin_amdgcn_mfma_f32_16x16x32_bf16(a2.v, B2[8 + s], c2, 0, 0, 0);
        }
        #pragma unroll
        for (int r = 0; r < 4; r++) {
            ss0[r] += fmaxf(c0[r], 0.f);
            ss1[r] += fmaxf(c1[r], 0.f);
            ss2[r] += fmaxf(c2[r], 0.f);
        }
    }

    // ---- relayout s: C-layout -> [row][k] bf16 (stride 72) ----
    unsigned short* st = (unsigned short*)(pw + PW_ST);
    #pragma unroll
    for (int r = 0; r < 4; r++) {
        int row = quad * 4 + r;
        st[row * 72 + n16]      = bfbits(ss0[r]);
        st[row * 72 + 16 + n16] = bfbits(ss1[r]);
        st[row * 72 + 32 + n16] = bfbits(ss2[r]);   // cols 39..47 exact zeros
    }

    // ---- L3: A from st, B streamed from global (L2-resident) ----
    S8 A30, A31;
    A30.u = *(const uint4*)(st + n16 * 72 + quad * 8);
    A31.u = *(const uint4*)(st + n16 * 72 + 32 + quad * 8);
    const uint4* w3g = (const uint4*)(ws + G_W3F);
    unsigned short* x3t = (unsigned short*)(pw + PW_BUF);   // reuse BUF
    const float* b3p = (const float*)(ws + G_B3);
    #pragma unroll
    for (int nt = 0; nt < 8; nt++) {
        float bb = b3p[nt * 16 + n16];
        f32x4 c = {bb, bb, bb, bb};
        S8 bf0, bf1;
        bf0.u = w3g[(nt * 2 + 0) * 64 + lane];
        bf1.u = w3g[(nt * 2 + 1) * 64 + lane];
        c = __builtin_amdgcn_mfma_f32_16x16x32_bf16(A30.v, bf0.v, c, 0, 0, 0);
        c = __builtin_amdgcn_mfma_f32_16x16x32_bf16(A31.v, bf1.v, c, 0, 0, 0);
        #pragma unroll
        for (int r = 0; r < 4; r++)
            x3t[(quad * 4 + r) * 136 + nt * 16 + n16] = bfbits(fmaxf(c[r], 0.f));
    }

    // ---- heads: means|logvar (N=16) ----
    S8 Ah0, Ah1, Ah2, Ah3;
    Ah0.u = *(const uint4*)(x3t + n16 * 136 + 0  + quad * 8);
    Ah1.u = *(const uint4*)(x3t + n16 * 136 + 32 + quad * 8);
    Ah2.u = *(const uint4*)(x3t + n16 * 136 + 64 + quad * 8);
    Ah3.u = *(const uint4*)(x3t + n16 * 136 + 96 + quad * 8);
    float bmvv = *(const float*)(ws + G_BMV + n16 * 4);
    f32x4 cm = {bmvv, bmvv, bmvv, bmvv};
    {
        S8 bm0; bm0.u = *(const uint4*)(ws + G_MVF + (0 * 64 + lane) * 16);
        cm = __builtin_amdgcn_mfma_f32_16x16x32_bf16(Ah0.v, bm0.v, cm, 0, 0, 0);
        S8 bm1; bm1.u = *(const uint4*)(ws + G_MVF + (1 * 64 + lane) * 16);
        cm = __builtin_amdgcn_mfma_f32_16x16x32_bf16(Ah1.v, bm1.v, cm, 0, 0, 0);
        S8 bm2; bm2.u = *(const uint4*)(ws + G_MVF + (2 * 64 + lane) * 16);
        cm = __builtin_amdgcn_mfma_f32_16x16x32_bf16(Ah2.v, bm2.v, cm, 0, 0, 0);
        S8 bm3; bm3.u = *(const uint4*)(ws + G_MVF + (3 * 64 + lane) * 16);
        cm = __builtin_amdgcn_mfma_f32_16x16x32_bf16(Ah3.v, bm3.v, cm, 0, 0, 0);
    }
    float* mlv = (float*)(pw + PW_MH);
    #pragma unroll
    for (int r = 0; r < 4; r++) mlv[(quad * 4 + r) * 18 + n16] = cm[r];

    // ---- reparameterization + means/logvar/z outputs ----
    {
        int r = lane >> 2, g = lane & 3;
        long R = rb + r;
        const float* mrow = mlv + r * 18;
        float2 mn = *(const float2*)(mrow + 2 * g);
        float2 lv = *(const float2*)(mrow + 8 + 2 * g);
        float2 ev = *(const float2*)(eps + R * 8 + 2 * g);
        float z0 = fmaf(ev.x, __expf(0.5f * lv.x), mn.x);
        float z1 = fmaf(ev.y, __expf(0.5f * lv.y), mn.y);
        *(float2*)(out + (long)B * 12 + R * 8 + 2 * g) = mn;
        *(float2*)(out + (long)B * 20 + R * 8 + 2 * g) = lv;
        *(float2*)(out + (long)B * 28 + R * 8 + 2 * g) = make_float2(z0, z1);
        unsigned short* sic = (unsigned short*)(pw + PW_SIC);
        *(unsigned int*)(sic + r * 40 + 12 + 2 * g) = pk(z0, z1);  // k=12..19
    }

    // ---- decoder layer 1 (N=32, K=32) ----
    S8 Ad;
    Ad.u = *(const uint4*)((const unsigned short*)(pw + PW_SIC) + n16 * 40 + quad * 8);
    unsigned short* ht = (unsigned short*)(pw + PW_MH);   // reuse MH (mlv consumed)
    #pragma unroll
    for (int t = 0; t < 2; t++) {
        float dc = *(const float*)(ws + G_D1C + (t * 16 + n16) * 4);
        f32x4 c = {dc, dc, dc, dc};
        S8 bd; bd.u = *(const uint4*)(ws + G_D1F + (t * 64 + lane) * 16);
        c = __builtin_amdgcn_mfma_f32_16x16x32_bf16(Ad.v, bd.v, c, 0, 0, 0);
        #pragma unroll
        for (int r = 0; r < 4; r++)
            ht[(quad * 4 + r) * 40 + t * 16 + n16] = bfbits(fmaxf(c[r], 0.f));
    }

    // ---- decoder layer 2 (N=16, K=32) + sigmoid + recon store ----
    S8 Ah2d; Ah2d.u = *(const uint4*)(ht + n16 * 40 + quad * 8);
    float bd2v = *(const float*)(ws + G_BD2 + n16 * 4);
    f32x4 cr2 = {bd2v, bd2v, bd2v, bd2v};
    S8 b2d; b2d.u = *(const uint4*)(ws + G_D2F + lane * 16);
    cr2 = __builtin_amdgcn_mfma_f32_16x16x32_bf16(Ah2d.v, b2d.v, cr2, 0, 0, 0);
    if (n16 < 12) {
        #pragma unroll
        for (int r = 0; r < 4; r++)
            out[(rb + quad * 4 + r) * 12 + n16] = 1.f / (1.f + __expf(-cr2[r]));
    }
}

extern "C" void kernel_launch(void* const* d_in, const int* in_sizes, int n_in,
                              void* d_out, int out_size, void* d_ws, size_t ws_size,
                              hipStream_t stream) {
    const float* ic  = (const float*)d_in[0];   // initial_c [B,30]
    const float* cc  = (const float*)d_in[2];   // current_c [B,30]
    const float* eps = (const float*)d_in[3];   // eps [B,8]

    const int B = in_sizes[3] / 8;              // 262144
    const int nblocks = B / 64;                 // 4096

    prep_kernel<<<PREP_BLOCKS, TPB, 0, stream>>>(
        (const float*)d_in[4],  (const float*)d_in[5],
        (const float*)d_in[6],  (const float*)d_in[7],
        (const float*)d_in[8],  (const float*)d_in[9],
        (const float*)d_in[10], (const float*)d_in[11],
        (const float*)d_in[12], (const float*)d_in[13],
        (const float*)d_in[14], (const float*)d_in[15],
        (const float*)d_in[16], (const float*)d_in[17],
        (unsigned char*)d_ws);
    vae_mfma<<<nblocks, TPB, 0, stream>>>(
        ic, cc, eps, (const unsigned char*)d_ws, (float*)d_out, B);
}